// Round 1
// baseline (140.549 us; speedup 1.0000x reference)
//
#include <hip/hip_runtime.h>
#include <math.h>

namespace {

constexpr int   NPG    = 128;        // nodes per graph
constexpr int   NSITES = NPG * 7;    // 896 sites per graph
constexpr int   MTOT   = 4096;       // total nodes
constexpr float H      = 0.1f;

// W_FACTORS = sqrt((0.5^2 + sigma^2)/2), sigma in {0.4, 0.8, 1.2, 1.6}
constexpr float W0 = 0.45276925690687087f;
constexpr float W1 = 0.66708320320631664f;
constexpr float W2 = 0.91923881554251174f;
constexpr float W3 = 1.18532695911296985f;

constexpr float KCOUL   = 14.399645478425669f;  // e*1e10/eps0/(4*pi)
constexpr float HALF_L1 = 2.8867513459481287f;  // 0.5*sqrt(3)/0.3
constexpr float SQRTPI  = 1.7724538509055159f;

__device__ __forceinline__ float fast_rcp(float x)  { return __builtin_amdgcn_rcpf(x); }
__device__ __forceinline__ float fast_sqrt(float x) { return __builtin_amdgcn_sqrtf(x); }

// project (7 x 4) site-features S[j*4+r] -> 16 outputs
// k<4: l0 = S[0][k]; k>=4: q=k-4, r=q/3, comp=q%3; comp0:vy(2-5) comp1:vz(3-6) comp2:vx(1-4)
__device__ __forceinline__ float project_one(const float* S, int k) {
  if (k < 4) return S[k];
  int q = k - 4;
  int r = q / 3;
  int comp = q - 3 * r;
  int j1, j2;
  if (comp == 0)      { j1 = 2; j2 = 5; }
  else if (comp == 1) { j1 = 3; j2 = 6; }
  else                { j1 = 1; j2 = 4; }
  return HALF_L1 * (S[j1 * 4 + r] - S[j2 * 4 + r]);
}

__global__ __launch_bounds__(448) void es_features_kernel(
    const float* __restrict__ sf,   // (4096, 4)  source_feats
    const float* __restrict__ pos,  // (4096, 3)  node_positions
    float* __restrict__ out)        // [0:65536) features, [65536:131072) self_terms
{
  __shared__ float4 s_site[NSITES];  // xyz = site position, w = charge (0 for target node)
  __shared__ float  s_red[28];       // K_COUL * pair sums, [a*4+r]
  __shared__ float  s_self[28];      // self term, [j*4+r]
  __shared__ float  s_myc[7];        // target node's own (unmasked) charges

  const int m   = blockIdx.x;   // target node
  const int g   = m >> 7;       // graph
  const int n   = m & 127;      // node within graph
  const int tid = threadIdx.x;

  // ---- stage all sites of this graph into LDS (2 iterations of 448 threads) ----
  for (int s = tid; s < NSITES; s += 448) {
    int i = s / 7;
    int b = s - i * 7;
    int node = g * NPG + i;
    float px = pos[node * 3 + 0];
    float py = pos[node * 3 + 1];
    float pz = pos[node * 3 + 2];
    float ch;
    if (b == 0) {
      ch = sf[node * 4 + 0];
    } else {
      int ax = (b - 1) % 3;              // 0:x 1:y 2:z
      int comp = (ax == 0) ? 3 : ax;     // b1/b4 -> s3, b2/b5 -> s1, b3/b6 -> s2
      float sgn = (b >= 4) ? -5.0f : 5.0f;  // /t with t = 0.2, negated for back offsets
      ch = sf[node * 4 + comp] * sgn;
      float o = (b >= 4) ? -H : H;
      if (ax == 0)      px += o;
      else if (ax == 1) py += o;
      else              pz += o;
    }
    if (i == n) { s_myc[b] = ch; ch = 0.0f; }  // mask same-node pairs via zero charge
    s_site[s] = make_float4(px, py, pz, ch);
  }
  __syncthreads();

  // ---- each wave owns one target site a ----
  const int a    = tid >> 6;   // 0..6
  const int lane = tid & 63;
  const float4 t4 = s_site[n * 7 + a];
  const float ptx = t4.x, pty = t4.y, ptz = t4.z;

  const float k0 = 0.5f / W0, k1 = 0.5f / W1, k2 = 0.5f / W2, k3 = 0.5f / W3;

  float a0 = 0.f, a1 = 0.f, a2 = 0.f, a3 = 0.f;
#pragma unroll 2
  for (int it = 0; it < 14; ++it) {
    float4 s4 = s_site[it * 64 + lane];
    float dx = ptx - s4.x;
    float dy = pty - s4.y;
    float dz = ptz - s4.z;
    float d  = fast_sqrt(dx * dx + dy * dy + dz * dz);
    float cv = s4.w * fast_rcp(d + 1e-6f);   // charge * 1/(d+eps); 0 for own node
    a0 += cv * erff(d * k0);
    a1 += cv * erff(d * k1);
    a2 += cv * erff(d * k2);
    a3 += cv * erff(d * k3);
  }

  // wave-level reduction (64 lanes)
  for (int off = 32; off > 0; off >>= 1) {
    a0 += __shfl_down(a0, off, 64);
    a1 += __shfl_down(a1, off, 64);
    a2 += __shfl_down(a2, off, 64);
    a3 += __shfl_down(a3, off, 64);
  }
  if (lane == 0) {
    s_red[a * 4 + 0] = KCOUL * a0;
    s_red[a * 4 + 1] = KCOUL * a1;
    s_red[a * 4 + 2] = KCOUL * a2;
    s_red[a * 4 + 3] = KCOUL * a3;
  }
  __syncthreads();

  // ---- self term: sself[j][r] = K * sum_i c[i] * phi(cat(i,j), w_r) ----
  if (tid < 28) {
    int j = tid >> 2, r = tid & 3;
    float w = (r == 0) ? W0 : (r == 1) ? W1 : (r == 2) ? W2 : W3;
    float t0 = fast_rcp(w * SQRTPI);                                       // ds = 0
    float t1 = erff(0.05f / w) / (H + 1e-6f);                              // ds = h
    float t2 = erff(0.07071067811865475f / w) / (0.14142135623730951f + 1e-6f); // ds = h*sqrt2
    float t3 = erff(0.1f / w) / (0.2f + 1e-6f);                            // ds = 2h
    float sum = 0.f;
    for (int i = 0; i < 7; ++i) {
      float t;
      if (i == j)                          t = t0;
      else if (i == 0 || j == 0)           t = t1;
      else if ((i - j == 3) || (j - i == 3)) t = t3;  // opposite offsets on same axis
      else                                 t = t2;    // different axes
      sum += s_myc[i] * t;
    }
    s_self[tid] = KCOUL * sum;
  }
  __syncthreads();

  // ---- projection + write: features = proj(pair) + proj(self); self_terms = proj(self) ----
  if (tid < 16) {
    float vs = project_one(s_self, tid);
    float vf = project_one(s_red, tid);
    out[m * 16 + tid]             = vf + vs;
    out[MTOT * 16 + m * 16 + tid] = vs;
  }
}

} // namespace

extern "C" void kernel_launch(void* const* d_in, const int* in_sizes, int n_in,
                              void* d_out, int out_size, void* d_ws, size_t ws_size,
                              hipStream_t stream) {
  const float* sf  = (const float*)d_in[0];   // source_feats (4096,1,4)
  const float* pos = (const float*)d_in[1];   // node_positions (4096,3)
  // d_in[2] = batch: implicit in layout (128 nodes per graph), unused
  float* out = (float*)d_out;
  es_features_kernel<<<MTOT, 448, 0, stream>>>(sf, pos, out);
}

// Round 2
// 100.841 us; speedup vs baseline: 1.3938x; 1.3938x over previous
//
#include <hip/hip_runtime.h>
#include <math.h>

namespace {

constexpr int   NPG    = 128;        // nodes per graph
constexpr int   NSITES = NPG * 7;    // 896 sites per graph
constexpr int   MTOT   = 4096;       // total nodes
constexpr float H      = 0.1f;

// W_FACTORS = sqrt((0.5^2 + sigma^2)/2), sigma in {0.4, 0.8, 1.2, 1.6}
constexpr float W0 = 0.45276925690687087f;
constexpr float W1 = 0.66708320320631664f;
constexpr float W2 = 0.91923881554251174f;
constexpr float W3 = 1.18532695911296985f;

constexpr float KCOUL   = 14.399645478425669f;  // e*1e10/eps0/(4*pi)
constexpr float HALF_L1 = 2.8867513459481287f;  // 0.5*sqrt(3)/0.3
constexpr float SQRTPI  = 1.7724538509055159f;

// k_r = 0.5/W_r ;  pk_r = 0.47047*k_r ;  c2_r = -k_r^2 * log2(e)
constexpr float PK0 = 0.5195472f, PK1 = 0.3526314f, PK2 = 0.2559019f, PK3 = 0.1984558f;
constexpr float K0  = 1.1043153f, K1  = 0.74953184f, K2 = 0.54392830f, K3 = 0.42182454f;
constexpr float C20 = -1.7593842f, C21 = -0.8105028f, C22 = -0.4268329f, C23 = -0.2567073f;
// A&S 7.1.25 coefficients (|err| <= 2.5e-5), note a1+a2+a3 == 1 exactly -> erf(0)=0
constexpr float EA1 = 0.3480242f, EA2 = -0.0958798f, EA3 = 0.7478556f;

__device__ __forceinline__ float fast_rcp(float x)  { return __builtin_amdgcn_rcpf(x); }
__device__ __forceinline__ float fast_rsq(float x)  { return __builtin_amdgcn_rsqf(x); }
__device__ __forceinline__ float fast_exp2(float x) { return __builtin_amdgcn_exp2f(x); }

// q(x) = (a1 t + a2 t^2 + a3 t^3) * e^{-x^2}  with  erf(x) = 1 - q(x), x >= 0.
// d = distance, d2 = d*d; pk = p*k_r, c2 = -k_r^2*log2e (x = d*k_r)
__device__ __forceinline__ float erf_q(float d, float d2, float pk, float c2) {
  float t = fast_rcp(__builtin_fmaf(d, pk, 1.0f));
  float poly = t * __builtin_fmaf(t, __builtin_fmaf(t, EA3, EA2), EA1);
  return poly * fast_exp2(d2 * c2);
}

// project (7 x 4) site-features S[j*4+r] -> 16 outputs
__device__ __forceinline__ float project_one(const float* S, int k) {
  if (k < 4) return S[k];
  int q = k - 4;
  int r = q / 3;
  int comp = q - 3 * r;
  int j1, j2;
  if (comp == 0)      { j1 = 2; j2 = 5; }
  else if (comp == 1) { j1 = 3; j2 = 6; }
  else                { j1 = 1; j2 = 4; }
  return HALF_L1 * (S[j1 * 4 + r] - S[j2 * 4 + r]);
}

__global__ __launch_bounds__(448) void es_features_kernel(
    const float* __restrict__ sf,   // (4096, 4)  source_feats
    const float* __restrict__ pos,  // (4096, 3)  node_positions
    float* __restrict__ out)        // [0:65536) features, [65536:131072) self_terms
{
  __shared__ float4 s_site[NSITES];  // xyz = site position, w = charge (0 for target node)
  __shared__ float  s_red[28];       // K_COUL * pair sums, [a*4+r]
  __shared__ float  s_self[28];      // self term, [j*4+r]
  __shared__ float  s_myc[7];        // target node's own (unmasked) charges

  const int m   = blockIdx.x;   // target node
  const int g   = m >> 7;       // graph
  const int n   = m & 127;      // node within graph
  const int tid = threadIdx.x;

  // ---- stage all sites of this graph into LDS ----
  for (int s = tid; s < NSITES; s += 448) {
    int i = s / 7;
    int b = s - i * 7;
    int node = g * NPG + i;
    float px = pos[node * 3 + 0];
    float py = pos[node * 3 + 1];
    float pz = pos[node * 3 + 2];
    float ch;
    if (b == 0) {
      ch = sf[node * 4 + 0];
    } else {
      int ax = (b - 1) % 3;              // 0:x 1:y 2:z
      int comp = (ax == 0) ? 3 : ax;     // b1/b4 -> s3, b2/b5 -> s1, b3/b6 -> s2
      float sgn = (b >= 4) ? -5.0f : 5.0f;  // /(2h) with h=0.1, negated for back offsets
      ch = sf[node * 4 + comp] * sgn;
      float o = (b >= 4) ? -H : H;
      if (ax == 0)      px += o;
      else if (ax == 1) py += o;
      else              pz += o;
    }
    if (i == n) { s_myc[b] = ch; ch = 0.0f; }  // mask same-node pairs via zero charge
    s_site[s] = make_float4(px, py, pz, ch);
  }
  __syncthreads();

  // ---- each wave owns one target site a ----
  const int a    = tid >> 6;   // 0..6
  const int lane = tid & 63;
  const float4 t4 = s_site[n * 7 + a];
  const float ptx = t4.x, pty = t4.y, ptz = t4.z;

  float S = 0.f;                                // sum of cv (the erf->1 part)
  float q0 = 0.f, q1 = 0.f, q2 = 0.f, q3 = 0.f; // sum of cv * q_r (the correction)
#pragma unroll
  for (int it = 0; it < 14; ++it) {
    float4 s4 = s_site[it * 64 + lane];
    float dx = ptx - s4.x;
    float dy = pty - s4.y;
    float dz = ptz - s4.z;
    float d2 = __builtin_fmaf(dx, dx, 1e-12f);
    d2 = __builtin_fmaf(dy, dy, d2);
    d2 = __builtin_fmaf(dz, dz, d2);
    float rd = fast_rsq(d2);        // 1/d  (self-pair: finite, charge=0 kills it)
    float d  = d2 * rd;             // d    (self-pair: ~0)
    float cv = s4.w * rd;           // charge / d
    S  += cv;
    q0 = __builtin_fmaf(cv, erf_q(d, d2, PK0, C20), q0);
    q1 = __builtin_fmaf(cv, erf_q(d, d2, PK1, C21), q1);
    q2 = __builtin_fmaf(cv, erf_q(d, d2, PK2, C22), q2);
    q3 = __builtin_fmaf(cv, erf_q(d, d2, PK3, C23), q3);
  }
  float a0 = S - q0, a1 = S - q1, a2 = S - q2, a3 = S - q3;

  // wave-level reduction (64 lanes)
  for (int off = 32; off > 0; off >>= 1) {
    a0 += __shfl_down(a0, off, 64);
    a1 += __shfl_down(a1, off, 64);
    a2 += __shfl_down(a2, off, 64);
    a3 += __shfl_down(a3, off, 64);
  }
  if (lane == 0) {
    s_red[a * 4 + 0] = KCOUL * a0;
    s_red[a * 4 + 1] = KCOUL * a1;
    s_red[a * 4 + 2] = KCOUL * a2;
    s_red[a * 4 + 3] = KCOUL * a3;
  }
  __syncthreads();

  // ---- self term: sself[j][r] = K * sum_i c[i] * phi(cat(i,j), w_r) ----
  if (tid < 28) {
    int j = tid >> 2, r = tid & 3;
    float w = (r == 0) ? W0 : (r == 1) ? W1 : (r == 2) ? W2 : W3;
    float t0 = fast_rcp(w * SQRTPI);                                       // ds = 0
    float t1 = erff(0.05f / w) / (H + 1e-6f);                              // ds = h
    float t2 = erff(0.07071067811865475f / w) / (0.14142135623730951f + 1e-6f); // ds = h*sqrt2
    float t3 = erff(0.1f / w) / (0.2f + 1e-6f);                            // ds = 2h
    float sum = 0.f;
    for (int i = 0; i < 7; ++i) {
      float t;
      if (i == j)                            t = t0;
      else if (i == 0 || j == 0)             t = t1;
      else if ((i - j == 3) || (j - i == 3)) t = t3;  // opposite offsets on same axis
      else                                   t = t2;  // different axes
      sum += s_myc[i] * t;
    }
    s_self[tid] = KCOUL * sum;
  }
  __syncthreads();

  // ---- projection + write ----
  if (tid < 16) {
    float vs = project_one(s_self, tid);
    float vf = project_one(s_red, tid);
    out[m * 16 + tid]             = vf + vs;
    out[MTOT * 16 + m * 16 + tid] = vs;
  }
}

} // namespace

extern "C" void kernel_launch(void* const* d_in, const int* in_sizes, int n_in,
                              void* d_out, int out_size, void* d_ws, size_t ws_size,
                              hipStream_t stream) {
  const float* sf  = (const float*)d_in[0];   // source_feats (4096,1,4)
  const float* pos = (const float*)d_in[1];   // node_positions (4096,3)
  float* out = (float*)d_out;
  es_features_kernel<<<MTOT, 448, 0, stream>>>(sf, pos, out);
}

// Round 3
// 95.064 us; speedup vs baseline: 1.4785x; 1.0608x over previous
//
#include <hip/hip_runtime.h>
#include <math.h>

namespace {

constexpr int   MTOT   = 4096;       // total nodes
constexpr float H      = 0.1f;

// W_FACTORS = sqrt((0.5^2 + sigma^2)/2), sigma in {0.4, 0.8, 1.2, 1.6}
constexpr float W0 = 0.45276925690687087f;
constexpr float W1 = 0.66708320320631664f;
constexpr float W2 = 0.91923881554251174f;
constexpr float W3 = 1.18532695911296985f;

constexpr float KCOUL   = 14.399645478425669f;  // e*1e10/eps0/(4*pi)
constexpr float HALF_L1 = 2.8867513459481287f;  // 0.5*sqrt(3)/0.3
constexpr float SQRTPI  = 1.7724538509055159f;

// pk_r = 0.47047*(0.5/W_r) ;  c2_r = -(0.5/W_r)^2 * log2(e)
constexpr float PK0 = 0.5195472f, PK1 = 0.3526314f, PK2 = 0.2559019f, PK3 = 0.1984558f;
constexpr float C20 = -1.7593842f, C21 = -0.8105028f, C22 = -0.4268329f, C23 = -0.2567073f;
// A&S 7.1.25 coefficients (|err| <= 2.5e-5); a1+a2+a3 == 1 -> erf(0)=0
constexpr float EA1 = 0.3480242f, EA2 = -0.0958798f, EA3 = 0.7478556f;

// 1/(ds + 1e-6) for ds = h, h*sqrt2, 2h
constexpr float RCP_H   = 9.9999000f;
constexpr float RCP_HS2 = 7.0710178f;
constexpr float RCP_2H  = 4.9999750f;

__device__ __forceinline__ float fast_rcp(float x)  { return __builtin_amdgcn_rcpf(x); }
__device__ __forceinline__ float fast_rsq(float x)  { return __builtin_amdgcn_rsqf(x); }
__device__ __forceinline__ float fast_exp2(float x) { return __builtin_amdgcn_exp2f(x); }

// q(x) = erfc(k*d) approx = (a1 t + a2 t^2 + a3 t^3) * e^{-(kd)^2}, t = 1/(1+p*k*d)
__device__ __forceinline__ float erf_q(float d, float d2, float pk, float c2) {
  float t = fast_rcp(__builtin_fmaf(d, pk, 1.0f));
  float poly = t * __builtin_fmaf(t, __builtin_fmaf(t, EA3, EA2), EA1);
  return poly * fast_exp2(d2 * c2);
}

// project (7 x 4) site-features S[j*4+r] -> 16 outputs
__device__ __forceinline__ float project_one(const float* S, int k) {
  if (k < 4) return S[k];
  int q = k - 4;
  int r = q / 3;
  int comp = q - 3 * r;
  int j1, j2;
  if (comp == 0)      { j1 = 2; j2 = 5; }
  else if (comp == 1) { j1 = 3; j2 = 6; }
  else                { j1 = 1; j2 = 4; }
  return HALF_L1 * (S[j1 * 4 + r] - S[j2 * 4 + r]);
}

// grid: 256 blocks = 32 graphs x 8 node-blocks; block: 896 thr = 112 sites x 8 chunks
__global__ __launch_bounds__(896, 4) void es_main(
    const float* __restrict__ sf,   // (4096, 4)
    const float* __restrict__ pos,  // (4096, 3)
    float* __restrict__ out)        // [0:65536) features, [65536:131072) self_terms
{
  __shared__ float4 s_site[896];      // whole graph's sites: xyz + charge
  __shared__ float4 s_part[8 * 112];  // per-chunk partial (a0..a3) per site
  __shared__ float  s_feat[112 * 4];  // per-site features (pair-corrected + self)
  __shared__ float  s_self[112 * 4];  // per-site self term

  const int b   = blockIdx.x;
  const int g   = b >> 3;    // graph
  const int nb  = b & 7;     // node-block: nodes [nb*16, nb*16+16) of graph
  const int tid = threadIdx.x;

  // ---- stage all 896 sites of this graph (one pass, no per-node masking) ----
  {
    const int s  = tid;
    const int i  = (s * 9363) >> 16;   // s/7 (exact for s < 896)
    const int bb = s - i * 7;
    const int node = g * 128 + i;
    float px = pos[node * 3 + 0];
    float py = pos[node * 3 + 1];
    float pz = pos[node * 3 + 2];
    float ch;
    if (bb == 0) {
      ch = sf[node * 4 + 0];
    } else {
      int ax = (bb - 1) % 3;                 // 0:x 1:y 2:z
      int comp = (ax == 0) ? 3 : ax;         // b1/b4 -> s3, b2/b5 -> s1, b3/b6 -> s2
      float sgn = (bb >= 4) ? -5.0f : 5.0f;  // 1/(2h), negated for back offsets
      ch = sf[node * 4 + comp] * sgn;
      float o = (bb >= 4) ? -H : H;
      if (ax == 0)      px += o;
      else if (ax == 1) py += o;
      else              pz += o;
    }
    s_site[s] = make_float4(px, py, pz, ch);
  }
  __syncthreads();

  // ---- main pair loop: thread = (target site, source chunk) ----
  const int site_local = tid % 112;
  const int chunk      = tid / 112;
  const int sl         = nb * 112 + site_local;   // target site within graph
  const float4 t4 = s_site[sl];
  const int src_base  = chunk * 112;
  const int cmp_local = sl - src_base;  // own-site index within this chunk (may be OOR)

  float S = 0.f, q0 = 0.f, q1 = 0.f, q2 = 0.f, q3 = 0.f;
  for (int it0 = 0; it0 < 112; it0 += 14) {
    const int tgt = cmp_local - it0;
#pragma unroll
    for (int u = 0; u < 14; ++u) {
      float4 s4 = s_site[src_base + it0 + u];  // <=2 distinct addrs per wave: broadcast
      float dx = t4.x - s4.x;
      float dy = t4.y - s4.y;
      float dz = t4.z - s4.z;
      float d2 = __builtin_fmaf(dx, dx, 1e-12f);
      d2 = __builtin_fmaf(dy, dy, d2);
      d2 = __builtin_fmaf(dz, dz, d2);
      float rd = fast_rsq(d2);
      float d  = d2 * rd;
      float cv = (u == tgt) ? 0.0f : s4.w * rd;  // mask only the singular own-site pair
      S += cv;
      q0 = __builtin_fmaf(cv, erf_q(d, d2, PK0, C20), q0);
      q1 = __builtin_fmaf(cv, erf_q(d, d2, PK1, C21), q1);
      q2 = __builtin_fmaf(cv, erf_q(d, d2, PK2, C22), q2);
      q3 = __builtin_fmaf(cv, erf_q(d, d2, PK3, C23), q3);
    }
  }
  s_part[chunk * 112 + site_local] = make_float4(S - q0, S - q1, S - q2, S - q3);
  __syncthreads();

  // ---- reduce chunks + self term + own-node correction (cancels to +c_a*diag) ----
  if (tid < 448) {
    const int site = tid >> 2;   // 0..111
    const int r    = tid & 3;
    const float* pf = (const float*)s_part;
    float tot = 0.f;
#pragma unroll
    for (int c = 0; c < 8; ++c) tot += pf[c * 448 + tid];

    const float w  = (r == 0) ? W0  : (r == 1) ? W1  : (r == 2) ? W2  : W3;
    const float pk = (r == 0) ? PK0 : (r == 1) ? PK1 : (r == 2) ? PK2 : PK3;
    const float c2 = (r == 0) ? C20 : (r == 1) ? C21 : (r == 2) ? C22 : C23;
    const float diag = fast_rcp(w * SQRTPI);
    const float ph1 = (1.f - erf_q(0.1f,         0.01f, pk, c2)) * RCP_H;
    const float ph2 = (1.f - erf_q(0.14142136f,  0.02f, pk, c2)) * RCP_HS2;
    const float ph3 = (1.f - erf_q(0.2f,         0.04f, pk, c2)) * RCP_2H;

    const int jn = (site * 9363) >> 16;  // node within block's 16 nodes
    const int ba = site - jn * 7;        // this site's offset index
    const int cbase = nb * 112 + jn * 7; // node's sites in s_site
    float selfSum = 0.f, ca = 0.f;
#pragma unroll
    for (int i = 0; i < 7; ++i) {
      float ci = s_site[cbase + i].w;
      float ph;
      if (i == ba)                           ph = diag;
      else if (i == 0 || ba == 0)            ph = ph1;
      else if ((i - ba == 3) || (ba - i == 3)) ph = ph3;
      else                                   ph = ph2;
      selfSum = __builtin_fmaf(ci, ph, selfSum);
      if (i == ba) ca = ci;
    }
    // features(site) = K*(tot - ownNodeOffDiag) + K*selfSum = K*(tot + c_a*diag)
    s_self[tid] = KCOUL * selfSum;
    s_feat[tid] = KCOUL * __builtin_fmaf(ca, diag, tot);
  }
  __syncthreads();

  // ---- projection + coalesced write (16 nodes x 16 outputs) ----
  if (tid < 256) {
    const int node = tid >> 4;
    const int k    = tid & 15;
    const int m    = g * 128 + nb * 16 + node;
    float vf = project_one(&s_feat[node * 28], k);
    float vs = project_one(&s_self[node * 28], k);
    out[m * 16 + k]           = vf;
    out[MTOT * 16 + m * 16 + k] = vs;
  }
}

} // namespace

extern "C" void kernel_launch(void* const* d_in, const int* in_sizes, int n_in,
                              void* d_out, int out_size, void* d_ws, size_t ws_size,
                              hipStream_t stream) {
  const float* sf  = (const float*)d_in[0];   // source_feats (4096,1,4)
  const float* pos = (const float*)d_in[1];   // node_positions (4096,3)
  float* out = (float*)d_out;
  es_main<<<256, 896, 0, stream>>>(sf, pos, out);
}